// Round 4
// baseline (433.391 us; speedup 1.0000x reference)
//
#include <hip/hip_runtime.h>

// SpikeLoss: loss = 0.5 * sum((outputs - psp(target))^2)
// psp: syn_t = syn_{t-1}*0.8 + x_t, emit syn_t/5   (tau=5)
// Shape [B=16, C=128, H=16, W=16, T=100], T contiguous. 524288 neurons.
//
// R4: LDS-transpose design. Block stages 64 neurons (25.6 KB) with perfect
// 64-lane float4-contiguous global loads; per-thread 25-step segment scan
// from LDS (bank-free mapping); 3-term carry composition (a^25); outputs
// staged into the SAME LDS region after B1 (26.6 KB/block -> 5-6 blocks/CU).
// No cross-lane shuffles on the critical path, no odd-shaped VMEM.

#define T_STEPS 100
#define SEG 25
#define NPB 64                           // neurons per block
#define BLOCK 256
#define N_NEURONS (16 * 128 * 16 * 16)   // 524288
#define GRID_P (N_NEURONS / NPB)         // 8192
#define F4_PER_CHUNK (NPB * T_STEPS / 4) // 1600 float4 per array per block

__device__ __forceinline__ float block_loss(const float* __restrict__ outputs,
                                            const float* __restrict__ target) {
  __shared__ float lbuf[NPB * T_STEPS];  // x staging, then reused for o
  __shared__ float lE[NPB * 4];          // segment-end syn, [4n+s]
  __shared__ float wsum[BLOCK / 64];

  const int tid = threadIdx.x;
  const size_t base = (size_t)blockIdx.x * (NPB * T_STEPS);
  const float4* gt = reinterpret_cast<const float4*>(target + base);
  const float4* go = reinterpret_cast<const float4*>(outputs + base);
  float4* lb4 = reinterpret_cast<float4*>(lbuf);

  // ---- Phase A1: stage target, fully coalesced, loads batched ----
  float4 bt[6];
#pragma unroll
  for (int k = 0; k < 6; ++k) bt[k] = gt[tid + 256 * k];
  float4 tt = make_float4(0.f, 0.f, 0.f, 0.f);
  if (tid < F4_PER_CHUNK - 1536) tt = gt[1536 + tid];
#pragma unroll
  for (int k = 0; k < 6; ++k) lb4[tid + 256 * k] = bt[k];
  if (tid < F4_PER_CHUNK - 1536) lb4[1536 + tid] = tt;

  // issue outputs loads now; they drain at the next barrier (harmless)
  float4 bo[6];
#pragma unroll
  for (int k = 0; k < 6; ++k) bo[k] = go[tid + 256 * k];
  float4 to = make_float4(0.f, 0.f, 0.f, 0.f);
  if (tid < F4_PER_CHUNK - 1536) to = go[1536 + tid];

  __syncthreads();

  // ---- Phase B1: per-thread segment scan, x -> registers ----
  const int n = tid >> 2;  // neuron within block
  const int s = tid & 3;   // segment
  const float* xrow = lbuf + n * T_STEPS + s * SEG;  // 2-way banks: free
  float x[SEG];
#pragma unroll
  for (int j = 0; j < SEG; ++j) x[j] = xrow[j];
  float E = 0.f;
#pragma unroll
  for (int j = 0; j < SEG; ++j) E = fmaf(E, 0.8f, x[j]);
  lE[tid] = E;

  __syncthreads();  // x fully consumed to regs; lE visible

  // ---- Phase A2: stage outputs into the same LDS region ----
#pragma unroll
  for (int k = 0; k < 6; ++k) lb4[tid + 256 * k] = bo[k];
  if (tid < F4_PER_CHUNK - 1536) lb4[1536 + tid] = to;

  // carry into this segment = global syn at end of previous segment
  const float A25 = 3.77789319e-3f;   // 0.8^25
  const float A50 = 1.42724769e-5f;   // 0.8^50
  float carry = 0.f;
  if (s >= 1) carry = lE[tid - 1];
  if (s >= 2) carry = fmaf(A25, lE[tid - 2], carry);
  if (s >= 3) carry = fmaf(A50, lE[tid - 3], carry);

  __syncthreads();  // outputs visible

  // ---- Phase B2: rescan with carry seed; accumulate loss ----
  const float* orow = lbuf + n * T_STEPS + s * SEG;
  float syn = carry;
  float acc = 0.f;
#pragma unroll
  for (int j = 0; j < SEG; ++j) {
    syn = fmaf(syn, 0.8f, x[j]);
    float d = fmaf(-0.2f, syn, orow[j]);
    acc = fmaf(d, d, acc);
  }

  // ---- block reduction ----
#pragma unroll
  for (int off = 32; off > 0; off >>= 1) acc += __shfl_down(acc, off, 64);
  const int lane = tid & 63;
  const int wid = tid >> 6;
  if (lane == 0) wsum[wid] = acc;
  __syncthreads();
  return wsum[0] + wsum[1] + wsum[2] + wsum[3];
}

__global__ __launch_bounds__(BLOCK, 4) void spike_loss_partial(
    const float* __restrict__ outputs,
    const float* __restrict__ target,
    float* __restrict__ partial) {
  float blocksum = block_loss(outputs, target);
  if (threadIdx.x == 0) partial[blockIdx.x] = blocksum;
}

// Deterministic final reduction over per-block partials; applies the 0.5.
__global__ __launch_bounds__(256) void spike_loss_final(
    const float* __restrict__ partial, float* __restrict__ out, int nparts) {
  float acc = 0.0f;
  for (int i = threadIdx.x; i < nparts; i += 256) acc += partial[i];
#pragma unroll
  for (int off = 32; off > 0; off >>= 1) acc += __shfl_down(acc, off, 64);
  __shared__ float wsum[4];
  const int lane = threadIdx.x & 63;
  const int wid = threadIdx.x >> 6;
  if (lane == 0) wsum[wid] = acc;
  __syncthreads();
  if (threadIdx.x == 0) out[0] = 0.5f * (wsum[0] + wsum[1] + wsum[2] + wsum[3]);
}

// Fallback if d_ws is unusably small: atomic finish into d_out.
__global__ __launch_bounds__(BLOCK, 4) void spike_loss_atomic(
    const float* __restrict__ outputs,
    const float* __restrict__ target,
    float* __restrict__ out) {
  float blocksum = block_loss(outputs, target);
  if (threadIdx.x == 0) atomicAdd(out, 0.5f * blocksum);
}

extern "C" void kernel_launch(void* const* d_in, const int* in_sizes, int n_in,
                              void* d_out, int out_size, void* d_ws, size_t ws_size,
                              hipStream_t stream) {
  const float* outputs = (const float*)d_in[0];
  const float* target = (const float*)d_in[1];
  float* out = (float*)d_out;

  if (ws_size >= GRID_P * sizeof(float)) {
    float* partial = (float*)d_ws;
    spike_loss_partial<<<GRID_P, BLOCK, 0, stream>>>(outputs, target, partial);
    spike_loss_final<<<1, 256, 0, stream>>>(partial, out, GRID_P);
  } else {
    hipMemsetAsync(out, 0, sizeof(float), stream);
    spike_loss_atomic<<<GRID_P, BLOCK, 0, stream>>>(outputs, target, out);
  }
}

// Round 5
// 409.207 us; speedup vs baseline: 1.0591x; 1.0591x over previous
//
#include <hip/hip_runtime.h>

// SpikeLoss: loss = 0.5 * sum((outputs - psp(target))^2)
// psp: syn_t = syn_{t-1}*0.8 + x_t, emit syn_t/5   (tau=5)
// Shape [B=16, C=128, H=16, W=16, T=100], T contiguous. 524288 neurons.
//
// R5: R4's LDS-transpose structure, but staging via async DMA
// (__builtin_amdgcn_global_load_lds, width=16) -> NO VGPR staging arrays,
// no x[25] register array (B2 re-reads x from LDS). R4's 197 MB of scratch
// spill traffic (VGPR_Count=40 vs ~73 live) disappears.
// LDS: 2 x 25.6 KB buffers + 1 KB carries -> 3 blocks/CU; each block's full
// 51.2 KB is in flight before the barrier (async), so latency is covered by
// bytes-in-flight, not wave count.

#define T_STEPS 100
#define SEG 25
#define NPB 64                           // neurons per block
#define BLOCK 256
#define N_NEURONS (16 * 128 * 16 * 16)   // 524288
#define GRID_P (N_NEURONS / NPB)         // 8192
#define F4_PER_ARR (NPB * T_STEPS / 4)   // 1600 float4 per array per block

#define GLOBAL_AS __attribute__((address_space(1)))
#define LDS_AS __attribute__((address_space(3)))

__device__ __forceinline__ void async_f4(const float4* g, float4* l) {
  // DMA 16 B/lane global->LDS. LDS dest = wave-uniform base + lane*16;
  // passing per-lane pointers that already include lane*16 matches that.
  __builtin_amdgcn_global_load_lds((const GLOBAL_AS void*)g, (LDS_AS void*)l,
                                   16, 0, 0);
}

__device__ __forceinline__ float block_loss(const float* __restrict__ outputs,
                                            const float* __restrict__ target) {
  __shared__ float xbuf[NPB * T_STEPS];  // 25.6 KB
  __shared__ float obuf[NPB * T_STEPS];  // 25.6 KB
  __shared__ float lE[NPB * 4];          // segment-end syn, [4n+s]
  __shared__ float wsum[BLOCK / 64];

  const int tid = threadIdx.x;
  const size_t base = (size_t)blockIdx.x * (NPB * T_STEPS);
  const float4* gt = reinterpret_cast<const float4*>(target + base);
  const float4* go = reinterpret_cast<const float4*>(outputs + base);
  float4* lx4 = reinterpret_cast<float4*>(xbuf);
  float4* lo4 = reinterpret_cast<float4*>(obuf);

  // ---- Phase A: DMA both arrays into LDS (no VGPR round-trip) ----
#pragma unroll
  for (int it = 0; it < 6; ++it) async_f4(gt + it * 256 + tid, lx4 + it * 256 + tid);
  if (tid < F4_PER_ARR - 1536) async_f4(gt + 1536 + tid, lx4 + 1536 + tid);
#pragma unroll
  for (int it = 0; it < 6; ++it) async_f4(go + it * 256 + tid, lo4 + it * 256 + tid);
  if (tid < F4_PER_ARR - 1536) async_f4(go + 1536 + tid, lo4 + 1536 + tid);

  __syncthreads();  // drains vmcnt (DMA completion) + barrier

  // ---- Phase B1: per-thread segment scan from LDS ----
  // addr = n*100 + s*25 + j; for fixed j across a wave: banks 2-way -> free.
  const int n = tid >> 2;  // neuron within block
  const int s = tid & 3;   // segment
  const float* xrow = xbuf + n * T_STEPS + s * SEG;
  float E = 0.f;
#pragma unroll
  for (int j = 0; j < SEG; ++j) E = fmaf(E, 0.8f, xrow[j]);
  lE[tid] = E;

  __syncthreads();

  // carry into this segment = syn at end of previous segments (exact compose)
  const float A25 = 3.77789319e-3f;   // 0.8^25
  const float A50 = 1.42724769e-5f;   // 0.8^50
  float carry = 0.f;
  if (s >= 1) carry = lE[tid - 1];
  if (s >= 2) carry = fmaf(A25, lE[tid - 2], carry);
  if (s >= 3) carry = fmaf(A50, lE[tid - 3], carry);

  // ---- Phase B2: rescan with carry seed; accumulate loss ----
  const float* orow = obuf + n * T_STEPS + s * SEG;
  float syn = carry;
  float acc = 0.f;
#pragma unroll
  for (int j = 0; j < SEG; ++j) {
    syn = fmaf(syn, 0.8f, xrow[j]);
    float d = fmaf(-0.2f, syn, orow[j]);
    acc = fmaf(d, d, acc);
  }

  // ---- block reduction ----
#pragma unroll
  for (int off = 32; off > 0; off >>= 1) acc += __shfl_down(acc, off, 64);
  const int lane = tid & 63;
  const int wid = tid >> 6;
  if (lane == 0) wsum[wid] = acc;
  __syncthreads();
  return wsum[0] + wsum[1] + wsum[2] + wsum[3];
}

__global__ __launch_bounds__(BLOCK, 3) void spike_loss_partial(
    const float* __restrict__ outputs,
    const float* __restrict__ target,
    float* __restrict__ partial) {
  float blocksum = block_loss(outputs, target);
  if (threadIdx.x == 0) partial[blockIdx.x] = blocksum;
}

// Deterministic final reduction over per-block partials; applies the 0.5.
__global__ __launch_bounds__(256) void spike_loss_final(
    const float* __restrict__ partial, float* __restrict__ out, int nparts) {
  float acc = 0.0f;
  for (int i = threadIdx.x; i < nparts; i += 256) acc += partial[i];
#pragma unroll
  for (int off = 32; off > 0; off >>= 1) acc += __shfl_down(acc, off, 64);
  __shared__ float wsum[4];
  const int lane = threadIdx.x & 63;
  const int wid = threadIdx.x >> 6;
  if (lane == 0) wsum[wid] = acc;
  __syncthreads();
  if (threadIdx.x == 0) out[0] = 0.5f * (wsum[0] + wsum[1] + wsum[2] + wsum[3]);
}

// Fallback if d_ws is unusably small: atomic finish into d_out.
__global__ __launch_bounds__(BLOCK, 3) void spike_loss_atomic(
    const float* __restrict__ outputs,
    const float* __restrict__ target,
    float* __restrict__ out) {
  float blocksum = block_loss(outputs, target);
  if (threadIdx.x == 0) atomicAdd(out, 0.5f * blocksum);
}

extern "C" void kernel_launch(void* const* d_in, const int* in_sizes, int n_in,
                              void* d_out, int out_size, void* d_ws, size_t ws_size,
                              hipStream_t stream) {
  const float* outputs = (const float*)d_in[0];
  const float* target = (const float*)d_in[1];
  float* out = (float*)d_out;

  if (ws_size >= GRID_P * sizeof(float)) {
    float* partial = (float*)d_ws;
    spike_loss_partial<<<GRID_P, BLOCK, 0, stream>>>(outputs, target, partial);
    spike_loss_final<<<1, 256, 0, stream>>>(partial, out, GRID_P);
  } else {
    hipMemsetAsync(out, 0, sizeof(float), stream);
    spike_loss_atomic<<<GRID_P, BLOCK, 0, stream>>>(outputs, target, out);
  }
}